// Round 1
// baseline (262.658 us; speedup 1.0000x reference)
//
#include <hip/hip_runtime.h>
#include <stdint.h>

// Algebra (validated R3-R7): only the cls token queries.
//   q = x0 @ Wq + bq ; r_h = q_h @ Wk_h^T (blockdiag) ; logits = (r . x_n)/8
//   p = softmax ; y_h = sum_n p_h[n] x[n] ; ctx_h = y_h @ Wv_h + bv ; out = ctx @ Wo + bo
// R8: k-split gemm (4-row x 64-col block, waves own k-quarters, LDS reduce) for
// q/ctx/out; transpose+q merged into one launch.
// R9 (this round): logits+softmax+y fused into one per-bs kernel (attn_kernel):
//   - r loaded once per bs (was 8x across nt tiles) : -28 MiB traffic
//   - L round-trip eliminated (softmax lives in LDS)
//   - one fewer launch; x pass-2 temporally closer to pass-1 (better L2 re-hit)

// ---------------- gemm k-split body (shared by prep & standalone) ----------------
__device__ __forceinline__ void gemm_ks_body(
    const float* __restrict__ A, long a_row_stride, int a_col_off_mult,
    const float* __restrict__ W, const float* __restrict__ bias,
    float* __restrict__ C, int rt, int jt, int t,
    float (*a_s)[512], float (*red_s)[4][64]) {
  const int w = t >> 6, lane = t & 63;

  // stage A: 4 rows x 512
#pragma unroll
  for (int l = 0; l < 2; ++l) {
    int flat4 = t + l * 256;
    int arow = flat4 >> 7;
    int k4 = (flat4 & 127) * 4;
    float4 v = *(const float4*)&A[(long)(rt * 4 + arow) * a_row_stride +
                                  (long)jt * a_col_off_mult + k4];
    a_s[arow][k4] = v.x; a_s[arow][k4 + 1] = v.y;
    a_s[arow][k4 + 2] = v.z; a_s[arow][k4 + 3] = v.w;
  }
  __syncthreads();

  const int j = jt * 64 + lane;
  float acc0 = 0.f, acc1 = 0.f, acc2 = 0.f, acc3 = 0.f;
  const float* wp = W + (long)(w * 128) * 512 + j;
  const float* ap = &a_s[0][w * 128];
#pragma unroll 8
  for (int k = 0; k < 128; ++k) {
    float wv = wp[(long)k * 512];
    acc0 += ap[k] * wv;
    acc1 += ap[512 + k] * wv;
    acc2 += ap[1024 + k] * wv;
    acc3 += ap[1536 + k] * wv;
  }
  if (w > 0) {
    red_s[w - 1][0][lane] = acc0;
    red_s[w - 1][1][lane] = acc1;
    red_s[w - 1][2][lane] = acc2;
    red_s[w - 1][3][lane] = acc3;
  }
  __syncthreads();
  if (w == 0) {
#pragma unroll
    for (int rr = 0; rr < 3; ++rr) {
      acc0 += red_s[rr][0][lane];
      acc1 += red_s[rr][1][lane];
      acc2 += red_s[rr][2][lane];
      acc3 += red_s[rr][3][lane];
    }
    const float b = bias[j];
    C[(long)(rt * 4 + 0) * 512 + j] = acc0 + b;
    C[(long)(rt * 4 + 1) * 512 + j] = acc1 + b;
    C[(long)(rt * 4 + 2) * 512 + j] = acc2 + b;
    C[(long)(rt * 4 + 3) * 512 + j] = acc3 + b;
  }
}

// ---------------- K1: merged transpose (blocks 0-255) + q gemm (256-767) -------
__global__ __launch_bounds__(256) void prep_kernel(
    const float* __restrict__ x, const float* __restrict__ Wq,
    const float* __restrict__ bq, const float* __restrict__ Wk,
    float* __restrict__ WkT, float* __restrict__ q) {
  __shared__ float a_s[4][512];
  __shared__ float red_s[3][4][64];
  const int t = threadIdx.x;

  if (blockIdx.x < 256) {
    float (*tile)[64] = (float(*)[64])&a_s[0][0];   // 32x33 fits in 8KB
    const int j0 = (blockIdx.x & 15) * 32;
    const int c0 = (blockIdx.x >> 4) * 32;
    {
      const int row = t >> 3;
      const int c4 = (t & 7) * 4;
      float4 v = *(const float4*)&Wk[(long)(j0 + row) * 512 + c0 + c4];
      float* tr = &tile[0][0] + row * 33;
      tr[c4] = v.x; tr[c4 + 1] = v.y; tr[c4 + 2] = v.z; tr[c4 + 3] = v.w;
    }
    __syncthreads();
    {
      const int row = t >> 3;
      const int j4 = (t & 7) * 4;
      const float* tb = &tile[0][0];
      float4 v = make_float4(tb[j4 * 33 + row], tb[(j4 + 1) * 33 + row],
                             tb[(j4 + 2) * 33 + row], tb[(j4 + 3) * 33 + row]);
      *(float4*)&WkT[(long)(c0 + row) * 512 + j0 + j4] = v;
    }
  } else {
    const int bid = blockIdx.x - 256;
    const int rt = bid & 63;
    const int jt = bid >> 6;
    gemm_ks_body(x, 131072L, 0, Wq, bq, q, rt, jt, t, a_s, red_s);
  }
}

// ---------------- standalone k-split gemm (ctx, out) ----------------
__global__ __launch_bounds__(256) void gemm_ks_kernel(
    const float* __restrict__ A, long a_row_stride, int a_col_off_mult,
    const float* __restrict__ W, const float* __restrict__ bias,
    float* __restrict__ C) {
  __shared__ float a_s[4][512];
  __shared__ float red_s[3][4][64];
  gemm_ks_body(A, a_row_stride, a_col_off_mult, W, bias, C,
               blockIdx.x, blockIdx.y, threadIdx.x, a_s, red_s);
}

// ---------------- r[256][4096]: r[s][h*512+jp] = q_h . WkT cols ----------------
__global__ __launch_bounds__(256) void r_kernel(
    const float* __restrict__ q, const float* __restrict__ WkT,
    float* __restrict__ r_all) {
  const int rt = blockIdx.x;
  const int h = blockIdx.y;
  const int t = threadIdx.x;
  __shared__ float q_s[4][64];

  {
    int row = t >> 6, c = t & 63;
    q_s[row][c] = q[(long)(rt * 4 + row) * 512 + h * 64 + c];
  }
  __syncthreads();

  const int jp4 = (t & 127) * 4;
  const int rh = t >> 7;
  float4 acc0 = make_float4(0.f, 0.f, 0.f, 0.f);
  float4 acc1 = make_float4(0.f, 0.f, 0.f, 0.f);
#pragma unroll 8
  for (int c = 0; c < 64; ++c) {
    float4 w4 = *(const float4*)&WkT[(long)(h * 64 + c) * 512 + jp4];
    float q0 = q_s[rh * 2][c], q1 = q_s[rh * 2 + 1][c];
    acc0.x += q0 * w4.x; acc0.y += q0 * w4.y; acc0.z += q0 * w4.z; acc0.w += q0 * w4.w;
    acc1.x += q1 * w4.x; acc1.y += q1 * w4.y; acc1.z += q1 * w4.z; acc1.w += q1 * w4.w;
  }
  *(float4*)&r_all[(long)(rt * 4 + rh * 2) * 4096 + h * 512 + jp4] = acc0;
  *(float4*)&r_all[(long)(rt * 4 + rh * 2 + 1) * 4096 + h * 512 + jp4] = acc1;
}

// ---------------- fused logits + softmax + y : one block per bs ----------------
// 1024 threads = 16 waves. Pass1: wave w computes logits for n = w*16..w*16+15
// (proven dot+shuffle-reduce from the old logits_kernel), into LDS.
// Softmax: wave w<8 normalizes head w in LDS. Pass2: thread (d = t&511,
// half = t>>9) accumulates y over its n-half (proven y_kernel pattern).
__global__ __launch_bounds__(1024) void attn_kernel(
    const float* __restrict__ x, const float* __restrict__ r_all,
    float* __restrict__ Y) {
  const int bs = blockIdx.x;
  const int t = threadIdx.x;
  const int w = t >> 6, lane = t & 63;
  __shared__ float p_s[8][256];   // logits, then probabilities
  __shared__ float yp[8][512];    // pass-2 partials from half 1

  // ---- pass 1: logits ----
  float rv[8][8];
  const float* rb = r_all + (long)bs * 4096 + lane * 8;
#pragma unroll
  for (int h = 0; h < 8; ++h) {
    float4 a = *(const float4*)&rb[h * 512];
    float4 b = *(const float4*)&rb[h * 512 + 4];
    rv[h][0] = a.x; rv[h][1] = a.y; rv[h][2] = a.z; rv[h][3] = a.w;
    rv[h][4] = b.x; rv[h][5] = b.y; rv[h][6] = b.z; rv[h][7] = b.w;
  }

  const int l4 = lane & 4, l2 = lane & 2, l1 = lane & 1;
#pragma unroll 4
  for (int i = 0; i < 16; ++i) {
    const int n = w * 16 + i;
    const float* xr = x + ((long)bs * 256 + n) * 512 + lane * 8;
    float4 xa = *(const float4*)xr;
    float4 xb = *(const float4*)(xr + 4);
    float acc[8];
#pragma unroll
    for (int h = 0; h < 8; ++h)
      acc[h] = xa.x * rv[h][0] + xa.y * rv[h][1] + xa.z * rv[h][2] + xa.w * rv[h][3]
             + xb.x * rv[h][4] + xb.y * rv[h][5] + xb.z * rv[h][6] + xb.w * rv[h][7];
#pragma unroll
    for (int j = 0; j < 4; ++j) {
      float v = l4 ? acc[j] : acc[j + 4];
      float tt = __shfl_xor(v, 4);
      acc[j] = (l4 ? acc[j + 4] : acc[j]) + tt;
    }
#pragma unroll
    for (int j = 0; j < 2; ++j) {
      float v = l2 ? acc[j] : acc[j + 2];
      float tt = __shfl_xor(v, 2);
      acc[j] = (l2 ? acc[j + 2] : acc[j]) + tt;
    }
    {
      float v = l1 ? acc[0] : acc[1];
      float tt = __shfl_xor(v, 1);
      acc[0] = (l1 ? acc[1] : acc[0]) + tt;
    }
    acc[0] += __shfl_xor(acc[0], 8);
    acc[0] += __shfl_xor(acc[0], 16);
    acc[0] += __shfl_xor(acc[0], 32);
    if (lane < 8)
      p_s[lane][n] = acc[0] * 0.125f;
  }
  __syncthreads();

  // ---- softmax: wave w < 8 handles head w ----
  if (w < 8) {
    float4 lv = *(const float4*)&p_s[w][lane * 4];
    float m = fmaxf(fmaxf(lv.x, lv.y), fmaxf(lv.z, lv.w));
    for (int o = 32; o; o >>= 1) m = fmaxf(m, __shfl_xor(m, o));
    float e0 = __expf(lv.x - m), e1 = __expf(lv.y - m);
    float e2 = __expf(lv.z - m), e3 = __expf(lv.w - m);
    float s = e0 + e1 + e2 + e3;
    for (int o = 32; o; o >>= 1) s += __shfl_xor(s, o);
    const float inv = 1.f / s;
    *(float4*)&p_s[w][lane * 4] = make_float4(e0 * inv, e1 * inv, e2 * inv, e3 * inv);
  }
  __syncthreads();

  // ---- pass 2: y_h[d] = sum_n p[h][n] x[n][d], n split in halves ----
  const int d = t & 511;
  const int half = t >> 9;
  float acc[8] = {};
  const float* xb2 = x + ((long)bs * 256 + half * 128) * 512 + d;
#pragma unroll 8
  for (int n = 0; n < 128; ++n) {
    float xv = xb2[(long)n * 512];
#pragma unroll
    for (int h = 0; h < 8; ++h)
      acc[h] += p_s[h][half * 128 + n] * xv;
  }
  if (half == 1) {
#pragma unroll
    for (int h = 0; h < 8; ++h) yp[h][d] = acc[h];
  }
  __syncthreads();
  if (half == 0) {
#pragma unroll
    for (int h = 0; h < 8; ++h)
      Y[(long)bs * 4096 + h * 512 + d] = acc[h] + yp[h][d];
  }
}

extern "C" void kernel_launch(void* const* d_in, const int* in_sizes, int n_in,
                              void* d_out, int out_size, void* d_ws, size_t ws_size,
                              hipStream_t stream) {
  (void)in_sizes; (void)n_in; (void)out_size; (void)ws_size;
  const float* x  = (const float*)d_in[0];
  const float* Wq = (const float*)d_in[1];
  const float* bq = (const float*)d_in[2];
  const float* Wk = (const float*)d_in[3];
  const float* bk = (const float*)d_in[4];  (void)bk;  // softmax-invariant
  const float* Wv = (const float*)d_in[5];
  const float* bv = (const float*)d_in[6];
  const float* Wo = (const float*)d_in[7];
  const float* bo = (const float*)d_in[8];
  float* out = (float*)d_out;

  float* WkT = (float*)d_ws;       // 512*512  = 1 MiB
  float* q   = WkT + 262144;       // 256*512  = 0.5 MiB
  float* r   = q + 131072;         // 256*4096 = 4 MiB
  float* Y   = r + 1048576;        // 256*4096 = 4 MiB
  float* ctx = Y + 1048576;        // 256*512  = 0.5 MiB

  prep_kernel<<<768, 256, 0, stream>>>(x, Wq, bq, Wk, WkT, q);
  r_kernel<<<dim3(64, 8), 256, 0, stream>>>(q, WkT, r);
  attn_kernel<<<256, 1024, 0, stream>>>(x, r, Y);
  gemm_ks_kernel<<<dim3(64, 8), 256, 0, stream>>>(Y, 4096L, 512, Wv, bv, ctx);
  gemm_ks_kernel<<<dim3(64, 8), 256, 0, stream>>>(ctx, 512L, 0, Wo, bo, out);
}